// Round 8
// baseline (1053.028 us; speedup 1.0000x reference)
//
#include <hip/hip_runtime.h>
#include <hip/hip_bf16.h>

#define DIV_UP(a,b) (((a)+(b)-1)/(b))

typedef __bf16 bf16x8 __attribute__((ext_vector_type(8)));
typedef float  f32x4  __attribute__((ext_vector_type(4)));

// ---- runtime dtype detector: bf16 data -> low 16b half of each word has a sane
// bf16 exponent; f32 data -> low half is mantissa garbage. flag=1 means bf16.
__global__ __launch_bounds__(256) void detect_dtype(const unsigned int* __restrict__ x,
                                                    int* __restrict__ flag) {
  __shared__ int cnt_s;
  if (threadIdx.x == 0) cnt_s = 0;
  __syncthreads();
  unsigned w = x[threadIdx.x];
  unsigned lo_exp = (w >> 7) & 0xFF;
  if (lo_exp >= 100 && lo_exp <= 140) atomicAdd(&cnt_s, 1);
  __syncthreads();
  if (threadIdx.x == 0) flag[0] = (cnt_s >= 128) ? 1 : 0;
}

// y[n,64] = x[n,K] @ w[64,K]^T via v_mfma_f32_16x16x32_bf16 (round-5 proven).
// xmode/wmode: 0 = f32 pointer, 1 = bf16 pointer, 2 = dual (use *flagp).
// Round-8: only used for layer 0 (K=128, f32/bf16 raw inputs).
template<int K>
__global__ __launch_bounds__(256) void gemm_mfma(
    const void* __restrict__ x, int xmode,
    const void* __restrict__ w, int woff, int wmode,
    const int* __restrict__ flagp, __hip_bfloat16* __restrict__ out, int n) {
  constexpr int KP = K + 8;
  __shared__ __bf16 xs[64 * KP];
  const bool xb = (xmode == 2) ? (*flagp != 0) : (xmode == 1);
  const bool wb = (wmode == 2) ? (*flagp != 0) : (wmode == 1);
  const int t = threadIdx.x;
  const int wv = t >> 6;
  const int L = t & 63;
  const int m = L & 15, q = L >> 4;
  const int row0 = blockIdx.x * 64;
  const int col = wv * 16 + m;

  bf16x8 bfr[K / 32];
  if (wb) {
    const __bf16* wh = (const __bf16*)w + woff;
#pragma unroll
    for (int ks = 0; ks < K / 32; ++ks)
      bfr[ks] = *(const bf16x8*)&wh[col * K + ks * 32 + q * 8];
  } else {
    const float* wf = (const float*)w + woff;
#pragma unroll
    for (int ks = 0; ks < K / 32; ++ks) {
      bf16x8 b;
#pragma unroll
      for (int j = 0; j < 8; ++j) b[j] = (__bf16)wf[col * K + ks * 32 + q * 8 + j];
      bfr[ks] = b;
    }
  }

  constexpr int CH = K / 8;
  if (xb) {
    const __bf16* xh = (const __bf16*)x;
    for (int idx = t; idx < 64 * CH; idx += 256) {
      int r = idx / CH, c = idx % CH;
      int gr = row0 + r; gr = (gr < n) ? gr : (n - 1);
      *(bf16x8*)&xs[r * KP + c * 8] = *(const bf16x8*)&xh[(size_t)gr * K + c * 8];
    }
  } else {
    const float* xf = (const float*)x;
    for (int idx = t; idx < 64 * CH; idx += 256) {
      int r = idx / CH, c = idx % CH;
      int gr = row0 + r; gr = (gr < n) ? gr : (n - 1);
      const float* src = &xf[(size_t)gr * K + c * 8];
      bf16x8 v;
#pragma unroll
      for (int j = 0; j < 8; ++j) v[j] = (__bf16)src[j];
      *(bf16x8*)&xs[r * KP + c * 8] = v;
    }
  }
  __syncthreads();

  f32x4 acc[4] = {};
#pragma unroll
  for (int ks = 0; ks < K / 32; ++ks) {
#pragma unroll
    for (int rt = 0; rt < 4; ++rt) {
      bf16x8 a = *(const bf16x8*)&xs[(rt * 16 + m) * KP + ks * 32 + q * 8];
      acc[rt] = __builtin_amdgcn_mfma_f32_16x16x32_bf16(a, bfr[ks], acc[rt], 0, 0, 0);
    }
  }

#pragma unroll
  for (int rt = 0; rt < 4; ++rt) {
#pragma unroll
    for (int i = 0; i < 4; ++i) {
      int gr = row0 + rt * 16 + q * 4 + i;
      if (gr < n) out[(size_t)gr * 64 + col] = __float2bfloat16(acc[rt][i]);
    }
  }
}

// ======== layer-0 fused kernel (round-7 proven, unchanged): lin_r MFMA +
// LDS-staged-col CSR gather of y + relu epilogue. ========
template<int K, int MODE, int NREL>
__global__ __launch_bounds__(256) void fused_agg(
    const void* __restrict__ xdst, int xmode,
    const int* __restrict__ flagp,
    const __hip_bfloat16* __restrict__ wrsum,
    const float* __restrict__ bias,
    const int* __restrict__ col,
    const int* __restrict__ rp0, const __hip_bfloat16* __restrict__ y0,
    const int* __restrict__ rp1, const __hip_bfloat16* __restrict__ y1,
    const int* __restrict__ rp2, const __hip_bfloat16* __restrict__ y2,
    float invR,
    void* __restrict__ outp, size_t obase, int n) {
  constexpr int CAP = 512;
  __shared__ float dbuf[16][68];
  __shared__ int rpl_s[NREL][17];
  __shared__ int cbuf[NREL][CAP];
  const bool xb = (xmode == 2) ? (*flagp != 0) : (xmode == 1);
  const int t = threadIdx.x;
  const int wv = t >> 6, L = t & 63;
  const int m = L & 15, q = L >> 4;
  const int row0 = blockIdx.x * 16;
  const int colc = wv * 16 + m;

  const int* rps[3] = {rp0, rp1, rp2};
  int hi16 = row0 + 16; hi16 = (hi16 < n) ? hi16 : n;
  int sj[NREL]; bool fit[NREL];
#pragma unroll
  for (int j = 0; j < NREL; ++j) {
    sj[j] = rps[j][row0];
    int span = rps[j][hi16] - sj[j];
    fit[j] = (span <= CAP);
    int lim = fit[j] ? span : 0;
    for (int i = t; i < lim; i += 256) cbuf[j][i] = col[sj[j] + i];
  }

  if (t < NREL * 17) {
    int j = t / 17, k = t - j * 17;
    const int* rp = (j == 0) ? rp0 : (j == 1) ? rp1 : rp2;
    int gi = row0 + k; gi = (gi < n) ? gi : n;
    rpl_s[j][k] = rp[gi];
  }

  const __bf16* wh = (const __bf16*)wrsum;
  bf16x8 bfr[K / 32];
#pragma unroll
  for (int ks = 0; ks < K / 32; ++ks)
    bfr[ks] = *(const bf16x8*)&wh[colc * K + ks * 32 + q * 8];

  int ar = row0 + m; ar = (ar < n) ? ar : (n - 1);
  f32x4 acc = {};
  if (xb) {
    const __bf16* xp = (const __bf16*)xdst;
#pragma unroll
    for (int ks = 0; ks < K / 32; ++ks) {
      bf16x8 a = *(const bf16x8*)&xp[(size_t)ar * K + ks * 32 + q * 8];
      acc = __builtin_amdgcn_mfma_f32_16x16x32_bf16(a, bfr[ks], acc, 0, 0, 0);
    }
  } else {
    const float* xp = (const float*)xdst;
#pragma unroll
    for (int ks = 0; ks < K / 32; ++ks) {
      bf16x8 a;
#pragma unroll
      for (int j = 0; j < 8; ++j) a[j] = (__bf16)xp[(size_t)ar * K + ks * 32 + q * 8 + j];
      acc = __builtin_amdgcn_mfma_f32_16x16x32_bf16(a, bfr[ks], acc, 0, 0, 0);
    }
  }
  float bc = bias[colc];
#pragma unroll
  for (int i = 0; i < 4; ++i) dbuf[q * 4 + i][colc] = acc[i] + bc;
  __syncthreads();

  const char* ys[3] = {(const char*)y0, (const char*)y1, (const char*)y2};
  const int jj = L & 31;
  const int half = L >> 5;
  const unsigned jb = (unsigned)jj << 2;

#pragma unroll 1
  for (int pass = 0; pass < 2; ++pass) {
    int b0[2][NREL], dg[2][NREL];
    float g0[2][NREL], g1[2][NREL];
    int nbmax = 0;
#pragma unroll
    for (int u = 0; u < 2; ++u) {
      const int lr = wv * 4 + pass * 2 + u;
#pragma unroll
      for (int j = 0; j < NREL; ++j) {
        int s = rpl_s[j][lr], e = rpl_s[j][lr + 1];
        b0[u][j] = s; dg[u][j] = e - s;
        g0[u][j] = 0.0f; g1[u][j] = 0.0f;
        int nbj = (e - s + 3) >> 2;
        nbmax = (nbj > nbmax) ? nbj : nbmax;
      }
    }

#pragma unroll 1
    for (int b = 0; b < nbmax; ++b) {
      const int bb = b << 2;
      unsigned wd[2][NREL][2];
#pragma unroll
      for (int u = 0; u < 2; ++u)
#pragma unroll
        for (int j = 0; j < NREL; ++j) {
          int rem = dg[u][j] - bb;
          if (rem > 0) {
            int last = rem - 1;
            int o0 = (half < last) ? half : last;
            int o1 = (2 + half < last) ? (2 + half) : last;
            unsigned c0, c1;
            if (fit[j]) {
              int lp = b0[u][j] - sj[j] + bb;
              c0 = (unsigned)cbuf[j][lp + o0];
              c1 = (unsigned)cbuf[j][lp + o1];
            } else {
              int p = b0[u][j] + bb;
              c0 = (unsigned)col[p + o0];
              c1 = (unsigned)col[p + o1];
            }
            wd[u][j][0] = *(const unsigned*)(ys[j] + ((c0 << 7) + jb));
            wd[u][j][1] = *(const unsigned*)(ys[j] + ((c1 << 7) + jb));
          }
        }
#pragma unroll
      for (int u = 0; u < 2; ++u)
#pragma unroll
        for (int j = 0; j < NREL; ++j) {
          int rem = dg[u][j] - bb;
          if (rem > 0) {
            unsigned w0 = (half < rem) ? wd[u][j][0] : 0u;
            unsigned w1 = (2 + half < rem) ? wd[u][j][1] : 0u;
            g0[u][j] += __uint_as_float(w0 << 16) + __uint_as_float(w1 << 16);
            g1[u][j] += __uint_as_float(w0 & 0xffff0000u) + __uint_as_float(w1 & 0xffff0000u);
          }
        }
    }

#pragma unroll
    for (int u = 0; u < 2; ++u) {
      const int lr = wv * 4 + pass * 2 + u;
      const int gr = row0 + lr;
      if (gr >= n) continue;
      float t0 = 0.0f, t1 = 0.0f;
#pragma unroll
      for (int j = 0; j < NREL; ++j) {
        float idg = (dg[u][j] > 0) ? (1.0f / (float)dg[u][j]) : 0.0f;
        t0 += g0[u][j] * idg; t1 += g1[u][j] * idg;
      }
      t0 += __shfl_xor(t0, 32, 64);
      t1 += __shfl_xor(t1, 32, 64);
      float2 d2 = *(const float2*)&dbuf[lr][2 * jj];
      float s0 = (d2.x + t0) * invR;
      float s1 = (d2.y + t1) * invR;

      if (MODE == 0) {
        if (half == 0) {
          __hip_bfloat16 b0v = __float2bfloat16(fmaxf(s0, 0.0f));
          __hip_bfloat16 b1v = __float2bfloat16(fmaxf(s1, 0.0f));
          unsigned pw = ((unsigned)*(const unsigned short*)&b1v << 16) |
                        (unsigned)*(const unsigned short*)&b0v;
          *(unsigned*)((__hip_bfloat16*)outp + obase + (size_t)gr * 64 + 2 * jj) = pw;
        }
      } else {
        float ss = s0 * s0 + s1 * s1;
#pragma unroll
        for (int o = 16; o > 0; o >>= 1) ss += __shfl_xor(ss, o, 64);
        float sc = 1.0f / fmaxf(sqrtf(ss), 1e-12f);
        float r0 = s0 * sc, r1 = s1 * sc;
        if (half == 0) {
          size_t idx = obase + (size_t)gr * 64 + 2 * jj;
          if (*flagp) {
            __hip_bfloat16 b0v = __float2bfloat16(r0);
            __hip_bfloat16 b1v = __float2bfloat16(r1);
            unsigned pw = ((unsigned)*(const unsigned short*)&b1v << 16) |
                          (unsigned)*(const unsigned short*)&b0v;
            *(unsigned*)((__hip_bfloat16*)outp + idx) = pw;
          } else {
            float2 v; v.x = r0; v.y = r1;
            *(float2*)((float*)outp + idx) = v;
          }
        }
      }
    }
  }
}

// ======== Round-8 NEW: aggregate-first fused kernel for layers 1-2 (K=64 bf16 h).
// Since lin_l is linear, mean_j(Wl h_j) = Wl mean_j(h_j): gather h_src directly
// (same random 128B rows as y), form per-relation aggregates a_r[16][64] in LDS,
// then 2 MFMAs per relation with Wl[r] -- ELIMINATES the per-relation y GEMMs
// (14 dispatches, ~220MB streaming). Gather loop = round-7 proven structure.
template<int MODE, int NREL>  // MODE 0: relu->bf16; MODE 1: l2norm->flag dtype
__global__ __launch_bounds__(256) void fused_pre(
    const __hip_bfloat16* __restrict__ xdst,   // h + toff[T] (bf16 always)
    const int* __restrict__ flagp,
    const void* __restrict__ Wl, int wo0, int wo1, int wo2,  // elem offsets per rel
    const __hip_bfloat16* __restrict__ wrsum,  // [64][64] merged lin_r (bf16)
    const float* __restrict__ bias,            // [64] merged
    const int* __restrict__ col,
    const int* __restrict__ rp0, const __hip_bfloat16* __restrict__ hs0,
    const int* __restrict__ rp1, const __hip_bfloat16* __restrict__ hs1,
    const int* __restrict__ rp2, const __hip_bfloat16* __restrict__ hs2,
    float invR, void* __restrict__ outp, size_t obase, int n) {
  constexpr int K = 64, CAP = 256;
  __shared__ float dbuf[16][68];
  __shared__ float abuf[NREL][16][68];   // per-relation aggregates (f32)
  __shared__ int rpl_s[NREL][17];
  __shared__ int cbuf[NREL][CAP];
  const bool wb = (*flagp != 0);
  const int t = threadIdx.x;
  const int wv = t >> 6, L = t & 63;
  const int m = L & 15, q = L >> 4;
  const int row0 = blockIdx.x * 16;
  const int colc = wv * 16 + m;

  // staging: cbuf spans + rowptr window (overlaps lin_r MFMA; barrier covers)
  const int* rps[3] = {rp0, rp1, rp2};
  int hi16 = row0 + 16; hi16 = (hi16 < n) ? hi16 : n;
  int sj[NREL]; bool fit[NREL];
#pragma unroll
  for (int j = 0; j < NREL; ++j) {
    sj[j] = rps[j][row0];
    int span = rps[j][hi16] - sj[j];
    fit[j] = (span <= CAP);
    int lim = fit[j] ? span : 0;
    for (int i = t; i < lim; i += 256) cbuf[j][i] = col[sj[j] + i];
  }
  if (t < NREL * 17) {
    int j = t / 17, k = t - j * 17;
    const int* rp = (j == 0) ? rp0 : (j == 1) ? rp1 : rp2;
    int gi = row0 + k; gi = (gi < n) ? gi : n;
    rpl_s[j][k] = rp[gi];
  }

  // lin_r MFMA (acc stays in registers until after the Wl MFMA phase)
  const __bf16* wh = (const __bf16*)wrsum;
  int ar = row0 + m; ar = (ar < n) ? ar : (n - 1);
  f32x4 acc = {};
  {
    const __bf16* xp = (const __bf16*)xdst;
#pragma unroll
    for (int ks = 0; ks < 2; ++ks) {
      bf16x8 bw = *(const bf16x8*)&wh[colc * K + ks * 32 + q * 8];
      bf16x8 a = *(const bf16x8*)&xp[(size_t)ar * K + ks * 32 + q * 8];
      acc = __builtin_amdgcn_mfma_f32_16x16x32_bf16(a, bw, acc, 0, 0, 0);
    }
  }
  __syncthreads();   // cbuf / rpl_s ready

  // gather h_src -> per-relation aggregates in abuf (round-7 loop structure)
  const char* hsb[3] = {(const char*)hs0, (const char*)hs1, (const char*)hs2};
  const int jj = L & 31;
  const int half = L >> 5;
  const unsigned jb = (unsigned)jj << 2;

#pragma unroll 1
  for (int pass = 0; pass < 2; ++pass) {
    int b0[2][NREL], dg[2][NREL];
    float g0[2][NREL], g1[2][NREL];
    int nbmax = 0;
#pragma unroll
    for (int u = 0; u < 2; ++u) {
      const int lr = wv * 4 + pass * 2 + u;
#pragma unroll
      for (int j = 0; j < NREL; ++j) {
        int s = rpl_s[j][lr], e = rpl_s[j][lr + 1];
        b0[u][j] = s; dg[u][j] = e - s;
        g0[u][j] = 0.0f; g1[u][j] = 0.0f;
        int nbj = (e - s + 3) >> 2;
        nbmax = (nbj > nbmax) ? nbj : nbmax;
      }
    }

#pragma unroll 1
    for (int b = 0; b < nbmax; ++b) {
      const int bb = b << 2;
      unsigned wd[2][NREL][2];
#pragma unroll
      for (int u = 0; u < 2; ++u)
#pragma unroll
        for (int j = 0; j < NREL; ++j) {
          int rem = dg[u][j] - bb;
          if (rem > 0) {
            int last = rem - 1;
            int o0 = (half < last) ? half : last;
            int o1 = (2 + half < last) ? (2 + half) : last;
            unsigned c0, c1;
            if (fit[j]) {
              int lp = b0[u][j] - sj[j] + bb;
              c0 = (unsigned)cbuf[j][lp + o0];
              c1 = (unsigned)cbuf[j][lp + o1];
            } else {
              int p = b0[u][j] + bb;
              c0 = (unsigned)col[p + o0];
              c1 = (unsigned)col[p + o1];
            }
            wd[u][j][0] = *(const unsigned*)(hsb[j] + ((c0 << 7) + jb));
            wd[u][j][1] = *(const unsigned*)(hsb[j] + ((c1 << 7) + jb));
          }
        }
#pragma unroll
      for (int u = 0; u < 2; ++u)
#pragma unroll
        for (int j = 0; j < NREL; ++j) {
          int rem = dg[u][j] - bb;
          if (rem > 0) {
            unsigned w0 = (half < rem) ? wd[u][j][0] : 0u;
            unsigned w1 = (2 + half < rem) ? wd[u][j][1] : 0u;
            g0[u][j] += __uint_as_float(w0 << 16) + __uint_as_float(w1 << 16);
            g1[u][j] += __uint_as_float(w0 & 0xffff0000u) + __uint_as_float(w1 & 0xffff0000u);
          }
        }
    }

    // write per-relation mean aggregates (zeros for empty/out-of-range rows)
#pragma unroll
    for (int u = 0; u < 2; ++u) {
      const int lr = wv * 4 + pass * 2 + u;
#pragma unroll
      for (int j = 0; j < NREL; ++j) {
        float idg = (dg[u][j] > 0) ? (1.0f / (float)dg[u][j]) : 0.0f;
        float t0 = g0[u][j] * idg, t1 = g1[u][j] * idg;
        t0 += __shfl_xor(t0, 32, 64);
        t1 += __shfl_xor(t1, 32, 64);
        if (half == 0) {
          abuf[j][lr][2 * jj] = t0;
          abuf[j][lr][2 * jj + 1] = t1;
        }
      }
    }
  }
  __syncthreads();   // abuf ready

  // Wl MFMA phase: acc += sum_j a_j @ Wl[j]^T   (2 MFMAs per relation)
  const int wos[3] = {wo0, wo1, wo2};
#pragma unroll
  for (int j = 0; j < NREL; ++j) {
#pragma unroll
    for (int ks = 0; ks < 2; ++ks) {
      bf16x8 bw;
      if (wb) {
        const __bf16* p = (const __bf16*)Wl + wos[j];
        bw = *(const bf16x8*)&p[colc * K + ks * 32 + q * 8];
      } else {
        const float* p = (const float*)Wl + wos[j];
#pragma unroll
        for (int e = 0; e < 8; ++e) bw[e] = (__bf16)p[colc * K + ks * 32 + q * 8 + e];
      }
      const float* arow = &abuf[j][m][ks * 32 + q * 8];
      bf16x8 ba;
#pragma unroll
      for (int e = 0; e < 8; ++e) ba[e] = (__bf16)arow[e];
      acc = __builtin_amdgcn_mfma_f32_16x16x32_bf16(ba, bw, acc, 0, 0, 0);
    }
  }

  float bc = bias[colc];
#pragma unroll
  for (int i = 0; i < 4; ++i) dbuf[q * 4 + i][colc] = acc[i] + bc;
  __syncthreads();

  // epilogue
#pragma unroll
  for (int rr = 0; rr < 4; ++rr) {
    const int lr = wv * 4 + rr;
    const int gr = row0 + lr;
    if (gr >= n) continue;                   // wave-uniform
    float2 d2 = *(const float2*)&dbuf[lr][2 * jj];
    float s0 = d2.x * invR;
    float s1 = d2.y * invR;
    if (MODE == 0) {
      if (half == 0) {
        __hip_bfloat16 b0v = __float2bfloat16(fmaxf(s0, 0.0f));
        __hip_bfloat16 b1v = __float2bfloat16(fmaxf(s1, 0.0f));
        unsigned pw = ((unsigned)*(const unsigned short*)&b1v << 16) |
                      (unsigned)*(const unsigned short*)&b0v;
        *(unsigned*)((__hip_bfloat16*)outp + obase + (size_t)gr * 64 + 2 * jj) = pw;
      }
    } else {
      float ss = s0 * s0 + s1 * s1;
#pragma unroll
      for (int o = 16; o > 0; o >>= 1) ss += __shfl_xor(ss, o, 64);
      float sc = 1.0f / fmaxf(sqrtf(ss), 1e-12f);
      float r0 = s0 * sc, r1 = s1 * sc;
      if (half == 0) {
        size_t idx = obase + (size_t)gr * 64 + 2 * jj;
        if (*flagp) {
          __hip_bfloat16 b0v = __float2bfloat16(r0);
          __hip_bfloat16 b1v = __float2bfloat16(r1);
          unsigned pw = ((unsigned)*(const unsigned short*)&b1v << 16) |
                        (unsigned)*(const unsigned short*)&b0v;
          *(unsigned*)((__hip_bfloat16*)outp + idx) = pw;
        } else {
          float2 v; v.x = r0; v.y = r1;
          *(float2*)((float*)outp + idx) = v;
        }
      }
    }
  }
}

// ======== CSR build (round-4 proven) ========
__global__ __launch_bounds__(256) void count_int(const int* __restrict__ ed,
                                                 int* __restrict__ deg, int E) {
  int i = blockIdx.x * 256 + threadIdx.x;
  if (i < E) atomicAdd(&deg[ed[i]], 1);
}

__global__ __launch_bounds__(256) void scan1(const int* __restrict__ deg,
    int* __restrict__ outp, int* __restrict__ part, int n) {
  __shared__ int tmp[256];
  int gid = blockIdx.x * 256 + threadIdx.x;
  int v = (gid < n) ? deg[gid] : 0;
  tmp[threadIdx.x] = v;
  __syncthreads();
  for (int off = 1; off < 256; off <<= 1) {
    int t = (threadIdx.x >= off) ? tmp[threadIdx.x - off] : 0;
    __syncthreads();
    tmp[threadIdx.x] += t;
    __syncthreads();
  }
  if (gid < n) outp[gid] = tmp[threadIdx.x] - v;  // exclusive
  if (threadIdx.x == 255) part[blockIdx.x] = tmp[255];
}

__global__ __launch_bounds__(256) void scan2(int* __restrict__ part, int P,
                                             int* __restrict__ totalout) {
  __shared__ int tmp[256];
  __shared__ int carry;
  if (threadIdx.x == 0) carry = 0;
  __syncthreads();
  for (int base0 = 0; base0 < P; base0 += 256) {
    int i = base0 + threadIdx.x;
    int v = (i < P) ? part[i] : 0;
    tmp[threadIdx.x] = v;
    __syncthreads();
    for (int off = 1; off < 256; off <<= 1) {
      int t = (threadIdx.x >= off) ? tmp[threadIdx.x - off] : 0;
      __syncthreads();
      tmp[threadIdx.x] += t;
      __syncthreads();
    }
    if (i < P) part[i] = tmp[threadIdx.x] - v + carry;
    __syncthreads();
    if (threadIdx.x == 0) carry += tmp[255];
    __syncthreads();
  }
  if (threadIdx.x == 0) *totalout = carry;
}

__global__ __launch_bounds__(256) void scan3(int* __restrict__ outp,
    const int* __restrict__ part, int n) {
  int gid = blockIdx.x * 256 + threadIdx.x;
  if (gid < n) outp[gid] += part[blockIdx.x];
}

__global__ __launch_bounds__(256) void copy_int(const int* __restrict__ src,
                                                int* __restrict__ dst, int n) {
  int i = blockIdx.x * 256 + threadIdx.x;
  if (i < n) dst[i] = src[i];
}

__global__ __launch_bounds__(256) void fill_csr(const int* __restrict__ es,
    const int* __restrict__ ed, int* __restrict__ cursor, int* __restrict__ col, int E) {
  int i = blockIdx.x * 256 + threadIdx.x;
  if (i < E) {
    int pos = atomicAdd(&cursor[ed[i]], 1);
    col[pos] = es[i];
  }
}

// wout(bf16) = W[o0] + W[o1] (+ W[o2]); bout(f32) similarly; offsets in elements
__global__ __launch_bounds__(256) void wsum_kernel(
    const void* __restrict__ W, int o0, int o1, int o2,
    const void* __restrict__ B, int p0, int p1, int p2,
    const int* __restrict__ flagp, __hip_bfloat16* __restrict__ wout,
    float* __restrict__ bout, int wsz) {
  const bool bf = (*flagp != 0);
  int i = blockIdx.x * 256 + threadIdx.x;
  float s = 0.0f, sb = 0.0f;
  if (bf) {
    const __hip_bfloat16* Wp = (const __hip_bfloat16*)W;
    const __hip_bfloat16* Bp = (const __hip_bfloat16*)B;
    if (i < wsz) {
      s = __bfloat162float(Wp[o0 + i]) + __bfloat162float(Wp[o1 + i]);
      if (o2 >= 0) s += __bfloat162float(Wp[o2 + i]);
    }
    if (i < 64) {
      sb = __bfloat162float(Bp[p0 + i]) + __bfloat162float(Bp[p1 + i]);
      if (p2 >= 0) sb += __bfloat162float(Bp[p2 + i]);
    }
  } else {
    const float* Wp = (const float*)W;
    const float* Bp = (const float*)B;
    if (i < wsz) {
      s = Wp[o0 + i] + Wp[o1 + i];
      if (o2 >= 0) s += Wp[o2 + i];
    }
    if (i < 64) {
      sb = Bp[p0 + i] + Bp[p1 + i];
      if (p2 >= 0) sb += Bp[p2 + i];
    }
  }
  if (i < wsz) wout[i] = __float2bfloat16(s);
  if (i < 64) bout[i] = sb;
}

extern "C" void kernel_launch(void* const* d_in, const int* in_sizes, int n_in,
                              void* d_out, int out_size, void* d_ws, size_t ws_size,
                              hipStream_t stream) {
  const int NC = 100000, NM = 50000, ND = 25000;
  const int nn[3] = {NC, NM, ND};
  const size_t toff[3] = {0, (size_t)NC * 64, (size_t)(NC + NM) * 64};
  const void* X[3] = {d_in[0], d_in[1], d_in[2]};
  const int* eptr[8]; int E[8];
  for (int r = 0; r < 8; ++r) { eptr[r] = (const int*)d_in[3 + r]; E[r] = in_sizes[3 + r] / 2; }
  const void* Wls[3] = {d_in[11], d_in[14], d_in[17]};
  const void* Wrs[3] = {d_in[12], d_in[15], d_in[18]};
  const void* Bbs[3] = {d_in[13], d_in[16], d_in[19]};

  // relation r: 0:c->m 1:m->d 2:c->d 3:m->c 4:d->m 5:d->c 6:c->c 7:m->m
  const int src_t[8] = {0, 1, 0, 1, 2, 2, 0, 1};
  const int dst_t[8] = {1, 2, 2, 0, 1, 0, 0, 1};
  // relations per dst type (3rd used only in layer 3 for T=0,1)
  const int relT[3][3] = {{3, 5, 6}, {0, 4, 7}, {1, 2, -1}};

  int coff[8]; int cntN = 0;
  for (int r = 0; r < 8; ++r) { coff[r] = cntN; cntN += nn[dst_t[r]]; }
  int Etot = 0; for (int r = 0; r < 8; ++r) Etot += E[r];

  // ---- workspace carve: 128B-aligned (round-6 proven: FETCH 143->79 MB) ----
  char* base = (char*)d_ws;
  auto carve = [&](size_t bytes) -> char* {
    char* p = (char*)(((uintptr_t)base + 127) & ~(uintptr_t)127);
    base = p + bytes;
    return p;
  };
  int* flag = (int*)carve(16);
  __hip_bfloat16* wr[3];
  for (int t = 0; t < 3; ++t) wr[t] = (__hip_bfloat16*)carve(64 * 128 * 2);
  float* bs[3]; for (int t = 0; t < 3; ++t) bs[t] = (float*)carve(64 * 4);
  __hip_bfloat16* y = (__hip_bfloat16*)carve((size_t)175000 * 64 * 2);  // layer-0 only
  int* degcur = (int*)carve((size_t)cntN * 4);
  int* rowptr = (int*)carve((size_t)(cntN + 1) * 4);
  int* part = (int*)carve((size_t)(DIV_UP(cntN, 256) + 1) * 4);
  int* col = (int*)carve((size_t)Etot * 4);
  __hip_bfloat16* h2 = (__hip_bfloat16*)carve((size_t)175000 * 64 * 2);
  __hip_bfloat16* h1 = (__hip_bfloat16*)d_out;  // prefix of d_out; dead before layer-3 writes
  (void)n_in; (void)out_size; (void)ws_size;

  detect_dtype<<<1, 256, 0, stream>>>((const unsigned int*)d_in[0], flag);

  // ---- CSR build (edges fixed; shared by all layers) ----
  hipMemsetAsync(degcur, 0, (size_t)cntN * sizeof(int), stream);
  for (int r = 0; r < 8; ++r)
    count_int<<<DIV_UP(E[r], 256), 256, 0, stream>>>(eptr[r] + E[r], degcur + coff[r], E[r]);
  int nb = DIV_UP(cntN, 256);
  scan1<<<nb, 256, 0, stream>>>(degcur, rowptr, part, cntN);
  scan2<<<1, 256, 0, stream>>>(part, nb, rowptr + cntN);
  scan3<<<nb, 256, 0, stream>>>(rowptr, part, cntN);
  copy_int<<<nb, 256, 0, stream>>>(rowptr, degcur, cntN);  // degcur -> cursor
  for (int r = 0; r < 8; ++r)
    fill_csr<<<DIV_UP(E[r], 256), 256, 0, stream>>>(eptr[r], eptr[r] + E[r],
                                                    degcur + coff[r], col, E[r]);

  // ---- layer 0: GEMM + gather-y path (f32/bf16 K=128 inputs) ----
  {
    const void* Wl = Wls[0];
    const void* Wr = Wrs[0];
    const void* Bb = Bbs[0];
    const int wsz = 64 * 128;
    for (int T = 0; T < 3; ++T) {
      const int r0 = relT[T][0], r1 = relT[T][1];
      wsum_kernel<<<DIV_UP(wsz, 256), 256, 0, stream>>>(
          Wr, r0 * wsz, r1 * wsz, -1, Bb, r0 * 64, r1 * 64, -1,
          flag, wr[T], bs[T], wsz);
      size_t yoffs[2] = {0, 0};
      size_t yoff = 0;
      for (int j = 0; j < 2; ++j) {
        int r = relT[T][j], st = src_t[r];
        yoffs[j] = yoff;
        gemm_mfma<128><<<DIV_UP(nn[st], 64), 256, 0, stream>>>(
            X[st], 2, Wl, r * wsz, 2, flag, y + yoff, nn[st]);
        yoff += (size_t)nn[st] * 64;
      }
      const int* rp0 = rowptr + coff[r0];
      const int* rp1 = rowptr + coff[r1];
      int grid = DIV_UP(nn[T], 16);
      fused_agg<128, 0, 2><<<grid, 256, 0, stream>>>(
          X[T], 2, flag, wr[T], bs[T], col, rp0, y + yoffs[0], rp1, y + yoffs[1],
          rp0, y + yoffs[0], 0.5f, h1, toff[T], nn[T]);
    }
  }

  // ---- layers 1 & 2: aggregate-first (no y GEMMs) ----
  for (int layer = 1; layer < 3; ++layer) {
    const void* Wl = Wls[layer];
    const void* Wr = Wrs[layer];
    const void* Bb = Bbs[layer];
    const int wsz = 64 * 64;
    const __hip_bfloat16* hin = (layer == 1) ? h1 : h2;

    for (int T = 0; T < 3; ++T) {
      const int nrel = (layer == 2 && T < 2) ? 3 : 2;
      const int r0 = relT[T][0], r1 = relT[T][1];
      const int r2 = (nrel == 3) ? relT[T][2] : -1;
      wsum_kernel<<<DIV_UP(wsz, 256), 256, 0, stream>>>(
          Wr, r0 * wsz, r1 * wsz, (r2 >= 0) ? r2 * wsz : -1,
          Bb, r0 * 64, r1 * 64, (r2 >= 0) ? r2 * 64 : -1,
          flag, wr[T], bs[T], wsz);
      const int* rp0 = rowptr + coff[r0];
      const int* rp1 = rowptr + coff[r1];
      const int* rp2 = (r2 >= 0) ? rowptr + coff[r2] : rp0;
      const __hip_bfloat16* g0p = hin + toff[src_t[r0]];
      const __hip_bfloat16* g1p = hin + toff[src_t[r1]];
      const __hip_bfloat16* g2p = (r2 >= 0) ? hin + toff[src_t[r2]] : g0p;
      int grid = DIV_UP(nn[T], 16);
      if (layer == 1) {
        fused_pre<0, 2><<<grid, 256, 0, stream>>>(
            hin + toff[T], flag, Wl, r0 * wsz, r1 * wsz, -1,
            wr[T], bs[T], col, rp0, g0p, rp1, g1p, rp0, g0p,
            0.5f, h2, toff[T], nn[T]);
      } else if (T < 2) {
        fused_pre<1, 3><<<grid, 256, 0, stream>>>(
            hin + toff[T], flag, Wl, r0 * wsz, r1 * wsz, r2 * wsz,
            wr[T], bs[T], col, rp0, g0p, rp1, g1p, rp2, g2p,
            1.0f / 3.0f, d_out, toff[T], nn[T]);
      } else {
        fused_pre<1, 2><<<grid, 256, 0, stream>>>(
            hin + toff[T], flag, Wl, r0 * wsz, r1 * wsz, -1,
            wr[T], bs[T], col, rp0, g0p, rp1, g1p, rp0, g0p,
            0.5f, d_out, toff[T], nn[T]);
      }
    }
  }
}